// Round 1
// baseline (772.734 us; speedup 1.0000x reference)
//
#include <hip/hip_runtime.h>
#include <stdint.h>

#define N_TOK 2048
#define C_DIM 1024
#define H_DIM 2048
#define NE 8
#define NSLOT 3
#define BM 64
#define BN 64
#define BK 32
#define AP 40   // A LDS row pitch (ushorts), padded vs 32 to spread banks
#define BP 36   // B^T LDS row pitch (ushorts)

// ws layout (bytes)
#define WS_COUNTS   0
#define WS_CW       256
#define WS_LISTS    (WS_CW + N_TOK*NE*4)
#define WS_XB       (WS_LISTS + NE*N_TOK*4)
#define WS_HBUF     (WS_XB + N_TOK*C_DIM*2)
#define WS_OUTSLOT  (WS_HBUF + (size_t)N_TOK*NSLOT*H_DIM*2)
// total ≈ 54.7 MB

typedef short bf16x8 __attribute__((ext_vector_type(8)));
typedef float f32x4 __attribute__((ext_vector_type(4)));

union FragU { bf16x8 v; uint2 u2[2]; };

__device__ __forceinline__ unsigned short f2b(float f) {
    union { float f; uint32_t u; } v; v.f = f;
    return (unsigned short)((v.u + 0x7fffu + ((v.u >> 16) & 1u)) >> 16); // RNE
}

__global__ void zero_kernel(int* counts) {
    if (threadIdx.x < NE) counts[threadIdx.x] = 0;
}

// One wave per token: logits (8 dots of len 1024), fp32 softmax, top-2 of
// experts 1..7, write cw row, build per-expert token lists, cast x row to bf16.
__global__ __launch_bounds__(256) void gate_kernel(
        const float* __restrict__ x, const float* __restrict__ gw,
        const float* __restrict__ gb, float* __restrict__ cw,
        unsigned short* __restrict__ xb, int* __restrict__ counts,
        int* __restrict__ lists) {
    int n = (blockIdx.x * 256 + threadIdx.x) >> 6;
    int lane = threadIdx.x & 63;
    if (n >= N_TOK) return;
    float acc[NE];
#pragma unroll
    for (int e = 0; e < NE; e++) acc[e] = 0.f;
    for (int c = lane; c < C_DIM; c += 64) {
        float xv = x[n * C_DIM + c];
        xb[n * C_DIM + c] = f2b(xv);
        const float* g = gw + c * NE;
#pragma unroll
        for (int e = 0; e < NE; e++) acc[e] += xv * g[e];
    }
#pragma unroll
    for (int e = 0; e < NE; e++) {
#pragma unroll
        for (int off = 32; off >= 1; off >>= 1) acc[e] += __shfl_xor(acc[e], off, 64);
        acc[e] += gb[e];
    }
    // softmax (monotone: exp precision cannot flip the top-k ordering)
    float m = acc[0];
#pragma unroll
    for (int e = 1; e < NE; e++) m = fmaxf(m, acc[e]);
    float s = 0.f, sc[NE];
#pragma unroll
    for (int e = 0; e < NE; e++) { sc[e] = __expf(acc[e] - m); s += sc[e]; }
    float inv = 1.f / s;
#pragma unroll
    for (int e = 0; e < NE; e++) sc[e] *= inv;
    // top-2 of routed experts 1..7; ties -> lower index (matches lax.top_k)
    int i1 = 1; float v1 = sc[1];
#pragma unroll
    for (int e = 2; e < NE; e++) if (sc[e] > v1) { v1 = sc[e]; i1 = e; }
    int i2 = 0; float v2 = -1.f;
#pragma unroll
    for (int e = 1; e < NE; e++) if (e != i1 && sc[e] > v2) { v2 = sc[e]; i2 = e; }
    if (lane < NE) {
        float v = 0.f;
        if (lane == 0) v = sc[0];
        else if (lane == i1) v = v1;
        else if (lane == i2) v = v2;
        cw[n * NE + lane] = v;
    }
    if (lane == 0) {  // entry = token*4 + slot
        int p0 = atomicAdd(&counts[0], 1);  lists[p0] = n * 4 + 0;
        int p1 = atomicAdd(&counts[i1], 1); lists[i1 * N_TOK + p1] = n * 4 + 1;
        int p2 = atomicAdd(&counts[i2], 1); lists[i2 * N_TOK + p2] = n * 4 + 2;
    }
}

// NOTE on fragment k-order: both A and B fragments use the SAME k-mapping
// (elems 0-3 <- k=4*(lane>>4)+j, elems 4-7 <- k=16+4*(lane>>4)+j). Since the
// MFMA contracts over all 32 k, any bijective k-permutation applied to BOTH
// operands gives the correct product; only m/n = lane&15 must be exact.

__global__ __launch_bounds__(256) void expert_up_kernel(
        const unsigned short* __restrict__ xb, const float* __restrict__ w1,
        const float* __restrict__ b1, const float* __restrict__ w3,
        const float* __restrict__ b3, const int* __restrict__ counts,
        const int* __restrict__ lists, unsigned short* __restrict__ hbuf) {
    const int e = blockIdx.z;
    const int cnt = counts[e];
    const int m0 = blockIdx.x * BM;
    if (m0 >= cnt) return;
    const int n0 = blockIdx.y * BN;
    const int t = threadIdx.x;
    const int lane = t & 63, wv = t >> 6;
    const int ln15 = lane & 15, lg = lane >> 4;

    __shared__ unsigned short As[BM * AP];
    __shared__ unsigned short B1s[BN * BP];
    __shared__ unsigned short B3s[BN * BP];
    __shared__ int rowtok[BM];

    if (t < BM) {
        int r = m0 + t;  // tail rows duplicate the last valid token: identical
        rowtok[t] = lists[e * N_TOK + (r < cnt ? r : cnt - 1)];  // values, benign dup writes
    }
    __syncthreads();

    f32x4 zero = {0.f, 0.f, 0.f, 0.f};
    f32x4 acc_a[4], acc_g[4];
#pragma unroll
    for (int i = 0; i < 4; i++) { acc_a[i] = zero; acc_g[i] = zero; }

    const size_t weoff = (size_t)e * C_DIM * H_DIM;
    const int ar = t >> 2, ac = (t & 3) * 8;   // A staging: 4 thr/row x 8 bf16
    const int btk = t >> 3, btn = (t & 7) * 8; // B staging: 8 thr/k-row x 8 fp32
    const int atok = rowtok[ar] >> 2;

    for (int k0 = 0; k0 < C_DIM; k0 += BK) {
        uint4 av = *(const uint4*)(xb + (size_t)atok * C_DIM + k0 + ac);
        const float* p1 = w1 + weoff + (size_t)(k0 + btk) * H_DIM + n0 + btn;
        const float* p3 = w3 + weoff + (size_t)(k0 + btk) * H_DIM + n0 + btn;
        float4 qa = *(const float4*)p1, qb = *(const float4*)(p1 + 4);
        float4 ra = *(const float4*)p3, rb = *(const float4*)(p3 + 4);
        float f1[8] = {qa.x, qa.y, qa.z, qa.w, qb.x, qb.y, qb.z, qb.w};
        float f3[8] = {ra.x, ra.y, ra.z, ra.w, rb.x, rb.y, rb.z, rb.w};
        __syncthreads();
        *(uint4*)(As + ar * AP + ac) = av;
#pragma unroll
        for (int i = 0; i < 8; i++) {  // transposed store: B^T[n][k]
            B1s[(btn + i) * BP + btk] = f2b(f1[i]);
            B3s[(btn + i) * BP + btk] = f2b(f3[i]);
        }
        __syncthreads();
        FragU af;
        af.u2[0] = *(const uint2*)(As + (wv * 16 + ln15) * AP + lg * 4);
        af.u2[1] = *(const uint2*)(As + (wv * 16 + ln15) * AP + 16 + lg * 4);
#pragma unroll
        for (int nt = 0; nt < 4; nt++) {
            FragU bf1, bf3;
            const unsigned short* q1 = B1s + (nt * 16 + ln15) * BP + lg * 4;
            const unsigned short* q3 = B3s + (nt * 16 + ln15) * BP + lg * 4;
            bf1.u2[0] = *(const uint2*)q1; bf1.u2[1] = *(const uint2*)(q1 + 16);
            bf3.u2[0] = *(const uint2*)q3; bf3.u2[1] = *(const uint2*)(q3 + 16);
            acc_a[nt] = __builtin_amdgcn_mfma_f32_16x16x32_bf16(af.v, bf1.v, acc_a[nt], 0, 0, 0);
            acc_g[nt] = __builtin_amdgcn_mfma_f32_16x16x32_bf16(af.v, bf3.v, acc_g[nt], 0, 0, 0);
        }
    }
#pragma unroll
    for (int nt = 0; nt < 4; nt++) {
        int col = n0 + nt * 16 + ln15;
        float bb1 = b1[e * H_DIM + col];
        float bb3 = b3[e * H_DIM + col];
#pragma unroll
        for (int j = 0; j < 4; j++) {
            int mrow = wv * 16 + lg * 4 + j;   // C/D layout: row=(lane>>4)*4+j
            float av2 = acc_a[nt][j] + bb1;
            float gv = acc_g[nt][j] + bb3;
            float hv = av2 * gv / (1.f + __expf(-gv));  // silu(g)*a
            int ent = rowtok[mrow];
            hbuf[(size_t)((ent >> 2) * NSLOT + (ent & 3)) * H_DIM + col] = f2b(hv);
        }
    }
}

__global__ __launch_bounds__(256) void expert_down_kernel(
        const unsigned short* __restrict__ hbuf, const float* __restrict__ w2,
        const float* __restrict__ b2, const float* __restrict__ cw,
        const int* __restrict__ counts, const int* __restrict__ lists,
        float* __restrict__ outslot) {
    const int e = blockIdx.z;
    const int cnt = counts[e];
    const int m0 = blockIdx.x * BM;
    if (m0 >= cnt) return;
    const int c0 = blockIdx.y * BN;
    const int t = threadIdx.x;
    const int lane = t & 63, wv = t >> 6;
    const int ln15 = lane & 15, lg = lane >> 4;

    __shared__ unsigned short As[BM * AP];
    __shared__ unsigned short Bs[BN * BP];
    __shared__ int rowtok[BM];

    if (t < BM) {
        int r = m0 + t;
        rowtok[t] = lists[e * N_TOK + (r < cnt ? r : cnt - 1)];
    }
    __syncthreads();

    f32x4 zero = {0.f, 0.f, 0.f, 0.f};
    f32x4 acc[4];
#pragma unroll
    for (int i = 0; i < 4; i++) acc[i] = zero;

    const size_t weoff = (size_t)e * H_DIM * C_DIM;
    const int ar = t >> 2, ac = (t & 3) * 8;
    const int btk = t >> 3, btn = (t & 7) * 8;
    const int aent = rowtok[ar];
    const size_t arow = (size_t)((aent >> 2) * NSLOT + (aent & 3)) * H_DIM;

    for (int k0 = 0; k0 < H_DIM; k0 += BK) {
        uint4 av = *(const uint4*)(hbuf + arow + k0 + ac);
        const float* p2 = w2 + weoff + (size_t)(k0 + btk) * C_DIM + c0 + btn;
        float4 qa = *(const float4*)p2, qb = *(const float4*)(p2 + 4);
        float fw[8] = {qa.x, qa.y, qa.z, qa.w, qb.x, qb.y, qb.z, qb.w};
        __syncthreads();
        *(uint4*)(As + ar * AP + ac) = av;
#pragma unroll
        for (int i = 0; i < 8; i++) Bs[(btn + i) * BP + btk] = f2b(fw[i]);
        __syncthreads();
        FragU af;
        af.u2[0] = *(const uint2*)(As + (wv * 16 + ln15) * AP + lg * 4);
        af.u2[1] = *(const uint2*)(As + (wv * 16 + ln15) * AP + 16 + lg * 4);
#pragma unroll
        for (int nt = 0; nt < 4; nt++) {
            FragU bf;
            const unsigned short* q = Bs + (nt * 16 + ln15) * BP + lg * 4;
            bf.u2[0] = *(const uint2*)q; bf.u2[1] = *(const uint2*)(q + 16);
            acc[nt] = __builtin_amdgcn_mfma_f32_16x16x32_bf16(af.v, bf.v, acc[nt], 0, 0, 0);
        }
    }
#pragma unroll
    for (int nt = 0; nt < 4; nt++) {
        int col = c0 + nt * 16 + ln15;
        float bb = b2[e * C_DIM + col];
#pragma unroll
        for (int j = 0; j < 4; j++) {
            int mrow = wv * 16 + lg * 4 + j;
            int ent = rowtok[mrow];
            int tok = ent >> 2, slot = ent & 3;
            float cwv = cw[tok * NE + e];
            outslot[(size_t)(tok * NSLOT + slot) * C_DIM + col] = cwv * (acc[nt][j] + bb);
        }
    }
}

__global__ __launch_bounds__(256) void reduce_kernel(
        const float* __restrict__ os, float* __restrict__ out) {
    int i = blockIdx.x * 256 + threadIdx.x;   // over N*C/4
    int n = i >> 8;
    int c = (i & 255) * 4;
    const float4 s0 = *(const float4*)(os + ((size_t)n * NSLOT + 0) * C_DIM + c);
    const float4 s1 = *(const float4*)(os + ((size_t)n * NSLOT + 1) * C_DIM + c);
    const float4 s2 = *(const float4*)(os + ((size_t)n * NSLOT + 2) * C_DIM + c);
    float4 r;
    r.x = s0.x + s1.x + s2.x; r.y = s0.y + s1.y + s2.y;
    r.z = s0.z + s1.z + s2.z; r.w = s0.w + s1.w + s2.w;
    *(float4*)(out + (size_t)n * C_DIM + c) = r;
}

__global__ void loss_kernel(const float* __restrict__ cw, const int* __restrict__ counts,
                            float* __restrict__ out) {
    int lane = threadIdx.x;
    float ss[NE];
#pragma unroll
    for (int e = 0; e < NE; e++) ss[e] = 0.f;
    for (int n = lane; n < N_TOK; n += 64) {
#pragma unroll
        for (int e = 0; e < NE; e++) ss[e] += cw[n * NE + e];
    }
#pragma unroll
    for (int e = 0; e < NE; e++) {
#pragma unroll
        for (int off = 32; off >= 1; off >>= 1) ss[e] += __shfl_xor(ss[e], off, 64);
    }
    if (lane == 0) {
        float bal = 0.f;
        const float fac = (float)NE / (3.f * (float)N_TOK * (float)N_TOK);
#pragma unroll
        for (int e = 0; e < NE; e++) bal += fac * (float)counts[e] * ss[e];
        out[(size_t)N_TOK * C_DIM] = bal;
    }
}

extern "C" void kernel_launch(void* const* d_in, const int* in_sizes, int n_in,
                              void* d_out, int out_size, void* d_ws, size_t ws_size,
                              hipStream_t stream) {
    const float* x  = (const float*)d_in[0];
    const float* gw = (const float*)d_in[1];
    const float* gb = (const float*)d_in[2];
    const float* w1 = (const float*)d_in[3];
    const float* b1 = (const float*)d_in[4];
    const float* w2 = (const float*)d_in[5];
    const float* b2 = (const float*)d_in[6];
    const float* w3 = (const float*)d_in[7];
    const float* b3 = (const float*)d_in[8];
    float* out = (float*)d_out;
    char* ws = (char*)d_ws;
    int*            counts = (int*)(ws + WS_COUNTS);
    float*          cw     = (float*)(ws + WS_CW);
    int*            lists  = (int*)(ws + WS_LISTS);
    unsigned short* xb     = (unsigned short*)(ws + WS_XB);
    unsigned short* hbuf   = (unsigned short*)(ws + WS_HBUF);
    float*          oslot  = (float*)(ws + WS_OUTSLOT);

    hipLaunchKernelGGL(zero_kernel, dim3(1), dim3(64), 0, stream, counts);
    hipLaunchKernelGGL(gate_kernel, dim3(N_TOK / 4), dim3(256), 0, stream,
                       x, gw, gb, cw, xb, counts, lists);
    hipLaunchKernelGGL(expert_up_kernel, dim3(N_TOK / BM, H_DIM / BN, NE), dim3(256), 0, stream,
                       xb, w1, b1, w3, b3, counts, lists, hbuf);
    hipLaunchKernelGGL(expert_down_kernel, dim3(N_TOK / BM, C_DIM / BN, NE), dim3(256), 0, stream,
                       hbuf, w2, b2, cw, counts, lists, oslot);
    hipLaunchKernelGGL(reduce_kernel, dim3((N_TOK * C_DIM / 4) / 256), dim3(256), 0, stream,
                       oslot, out);
    hipLaunchKernelGGL(loss_kernel, dim3(1), dim3(64), 0, stream, cw, counts, out);
}

// Round 2
// 400.781 us; speedup vs baseline: 1.9281x; 1.9281x over previous
//
#include <hip/hip_runtime.h>
#include <stdint.h>

#define N_TOK 2048
#define C_DIM 1024
#define H_DIM 2048
#define NE 8
#define NSLOT 3

#define BM 128
#define BN 128
#define BK 64

// ws layout (bytes); every section multiple of 256
#define WS_COUNTS   0
#define WS_CW       256
#define WS_LISTS    (WS_CW + N_TOK*NE*4)
#define WS_XB       (WS_LISTS + NE*N_TOK*4)
#define WS_HBUF     (WS_XB + (size_t)N_TOK*C_DIM*2)
#define WS_OUTSLOT  (WS_HBUF + (size_t)N_TOK*NSLOT*H_DIM*2)
#define WS_WT13     (WS_OUTSLOT + (size_t)N_TOK*NSLOT*C_DIM*4)
#define WS_WT2T     (WS_WT13 + (size_t)NE*2*H_DIM*C_DIM*2)
// total ≈ 154 MB

typedef short bf16x8 __attribute__((ext_vector_type(8)));
typedef float f32x4 __attribute__((ext_vector_type(4)));

union FragU { bf16x8 v; uint2 u2[2]; };

__device__ __forceinline__ unsigned short f2b(float f) {
    union { float f; uint32_t u; } v; v.f = f;
    return (unsigned short)((v.u + 0x7fffu + ((v.u >> 16) & 1u)) >> 16); // RNE
}

// async global->LDS, 16B per lane; lds dest is wave-uniform base + lane*16
__device__ __forceinline__ void gload16(const unsigned short* g, unsigned short* l) {
    __builtin_amdgcn_global_load_lds(
        (const __attribute__((address_space(1))) unsigned int*)g,
        (__attribute__((address_space(3))) unsigned int*)l, 16, 0, 0);
}

__global__ void zero_kernel(int* counts) {
    if (threadIdx.x < NE) counts[threadIdx.x] = 0;
}

// ---------------- gating: one wave per token ----------------
__global__ __launch_bounds__(256) void gate_kernel(
        const float* __restrict__ x, const float* __restrict__ gw,
        const float* __restrict__ gb, float* __restrict__ cw,
        unsigned short* __restrict__ xb, int* __restrict__ counts,
        int* __restrict__ lists) {
    int n = (blockIdx.x * 256 + threadIdx.x) >> 6;
    int lane = threadIdx.x & 63;
    if (n >= N_TOK) return;
    float acc[NE];
#pragma unroll
    for (int e = 0; e < NE; e++) acc[e] = 0.f;
    for (int c = lane; c < C_DIM; c += 64) {
        float xv = x[n * C_DIM + c];
        xb[n * C_DIM + c] = f2b(xv);
        const float* g = gw + c * NE;
#pragma unroll
        for (int e = 0; e < NE; e++) acc[e] += xv * g[e];
    }
#pragma unroll
    for (int e = 0; e < NE; e++) {
#pragma unroll
        for (int off = 32; off >= 1; off >>= 1) acc[e] += __shfl_xor(acc[e], off, 64);
        acc[e] += gb[e];
    }
    float m = acc[0];
#pragma unroll
    for (int e = 1; e < NE; e++) m = fmaxf(m, acc[e]);
    float s = 0.f, sc[NE];
#pragma unroll
    for (int e = 0; e < NE; e++) { sc[e] = __expf(acc[e] - m); s += sc[e]; }
    float inv = 1.f / s;
#pragma unroll
    for (int e = 0; e < NE; e++) sc[e] *= inv;
    // top-2 of routed experts 1..7; ties -> lower index (matches lax.top_k)
    int i1 = 1; float v1 = sc[1];
#pragma unroll
    for (int e = 2; e < NE; e++) if (sc[e] > v1) { v1 = sc[e]; i1 = e; }
    int i2 = 0; float v2 = -1.f;
#pragma unroll
    for (int e = 1; e < NE; e++) if (e != i1 && sc[e] > v2) { v2 = sc[e]; i2 = e; }
    if (lane < NE) {
        float v = 0.f;
        if (lane == 0) v = sc[0];
        else if (lane == i1) v = v1;
        else if (lane == i2) v = v2;
        cw[n * NE + lane] = v;
    }
    if (lane == 0) {  // entry = token*4 + slot
        int p0 = atomicAdd(&counts[0], 1);  lists[p0] = n * 4 + 0;
        int p1 = atomicAdd(&counts[i1], 1); lists[i1 * N_TOK + p1] = n * 4 + 1;
        int p2 = atomicAdd(&counts[i2], 1); lists[i2 * N_TOK + p2] = n * 4 + 2;
    }
}

// ---------- weight prepass: transpose + cast to bf16 B^T layout ----------
// src [E][K][N] fp32 -> dst [E][Nr][K] bf16, dest row r = ((n>>4)<<shift)+(n&15)+off
// w1: shift=5 off=0 ; w3: shift=5 off=16 (16-row interleave) ; w2: shift=4 off=0
__global__ __launch_bounds__(256) void tcast_kernel(
        const float* __restrict__ src, unsigned short* __restrict__ dst,
        int K, int N, int Nr, int shift, int off) {
    int e = blockIdx.z;
    int k0 = blockIdx.x * 64, n0 = blockIdx.y * 64;
    __shared__ unsigned short tile[64][72];
    const float* s = src + ((size_t)e * K + k0) * N + n0;
    int tr = threadIdx.x >> 4, tc = (threadIdx.x & 15) * 4;
#pragma unroll
    for (int i = 0; i < 4; i++) {
        float4 v = *(const float4*)(s + (size_t)(tr + i * 16) * N + tc);
        tile[tr + i * 16][tc + 0] = f2b(v.x);
        tile[tr + i * 16][tc + 1] = f2b(v.y);
        tile[tr + i * 16][tc + 2] = f2b(v.z);
        tile[tr + i * 16][tc + 3] = f2b(v.w);
    }
    __syncthreads();
    int hl = threadIdx.x >> 3, kl = (threadIdx.x & 7) * 8;
#pragma unroll
    for (int i = 0; i < 2; i++) {
        int hloc = hl + i * 32;
        int n = n0 + hloc;
        int r = ((n >> 4) << shift) + (n & 15) + off;
        unsigned short tmp[8];
#pragma unroll
        for (int q = 0; q < 8; q++) tmp[q] = tile[kl + q][hloc];
        *(uint4*)(dst + ((size_t)e * Nr + r) * K + k0 + kl) = *(uint4*)tmp;
    }
}

// ---------------- expert up: [tokens]x[w1|w3 interleaved] ----------------
// A = gathered xb rows (M=128), B = wt13 rows (N=128 combined), K = C, BK=64.
// LDS chunk swizzle: chunk c -> row=c>>3, slot=c&7, holds k-chunk kc=slot^(row&7).
__global__ __launch_bounds__(256) void expert_up_kernel(
        const unsigned short* __restrict__ xb, const unsigned short* __restrict__ wt13,
        const float* __restrict__ b1, const float* __restrict__ b3,
        const int* __restrict__ counts, const int* __restrict__ lists,
        unsigned short* __restrict__ hbuf) {
    const int e = blockIdx.z;
    const int cnt = counts[e];
    const int m0 = blockIdx.x * BM;
    if (m0 >= cnt) return;
    const int n0 = blockIdx.y * BN;
    const int t = threadIdx.x;
    const int lane = t & 63, w = t >> 6;
    const int ln15 = lane & 15, lg = lane >> 4;
    const int wr = w >> 1, wc = w & 1;

    __shared__ __align__(16) unsigned short As[BM * BK];
    __shared__ __align__(16) unsigned short Bs[BN * BK];
    __shared__ int rowtok[BM];

    if (t < BM) {
        int r = m0 + t;  // tail rows duplicate last valid token (benign dup writes)
        rowtok[t] = lists[e * N_TOK + (r < cnt ? r : cnt - 1)];
    }
    __syncthreads();

    const unsigned short* wtb = wt13 + (size_t)e * (2 * H_DIM) * C_DIM;
    const unsigned short* asrc[4];
    const unsigned short* bsrc[4];
#pragma unroll
    for (int i = 0; i < 4; i++) {
        int c = i * 256 + w * 64 + lane;         // LDS chunk index (16B units)
        int row = c >> 3, slot = c & 7, kc = slot ^ (row & 7);
        asrc[i] = xb + (size_t)(rowtok[row] >> 2) * C_DIM + kc * 8;
        bsrc[i] = wtb + (size_t)(n0 + row) * C_DIM + kc * 8;
    }

    f32x4 acc[4][4];
#pragma unroll
    for (int a = 0; a < 4; a++)
#pragma unroll
        for (int b = 0; b < 4; b++) acc[a][b] = (f32x4){0.f, 0.f, 0.f, 0.f};

    const int swz = ln15 & 7;
    for (int kt = 0; kt < C_DIM / BK; kt++) {
#pragma unroll
        for (int i = 0; i < 4; i++) {
            gload16(asrc[i], As + (i * 256 + w * 64) * 8);
            gload16(bsrc[i], Bs + (i * 256 + w * 64) * 8);
            asrc[i] += BK; bsrc[i] += BK;
        }
        __syncthreads();   // drains vmcnt(0): staged tile visible
#pragma unroll
        for (int j = 0; j < 2; j++) {
            FragU af[4], bf[4];
#pragma unroll
            for (int mt = 0; mt < 4; mt++) {
                int row = wr * 64 + mt * 16 + ln15;
                int slot = (j * 4 + lg) ^ swz;
                af[mt].v = *(const bf16x8*)(As + row * BK + slot * 8);
            }
#pragma unroll
            for (int nt = 0; nt < 4; nt++) {
                int row = wc * 64 + nt * 16 + ln15;
                int slot = (j * 4 + lg) ^ swz;
                bf[nt].v = *(const bf16x8*)(Bs + row * BK + slot * 8);
            }
#pragma unroll
            for (int mt = 0; mt < 4; mt++)
#pragma unroll
                for (int nt = 0; nt < 4; nt++)
                    acc[mt][nt] = __builtin_amdgcn_mfma_f32_16x16x32_bf16(
                        af[mt].v, bf[nt].v, acc[mt][nt], 0, 0, 0);
        }
        __syncthreads();   // before next-iter LDS overwrite
    }

    // epilogue: nt pairs (0,1),(2,3) are (a,g) for the same h column
#pragma unroll
    for (int p = 0; p < 2; p++) {
        int h = ((n0 + wc * 64 + p * 32) >> 5) * 16 + ln15;
        float bb1 = b1[e * H_DIM + h], bb3 = b3[e * H_DIM + h];
#pragma unroll
        for (int mt = 0; mt < 4; mt++) {
#pragma unroll
            for (int jj = 0; jj < 4; jj++) {
                int mrow = wr * 64 + mt * 16 + lg * 4 + jj;  // C/D: row=(lane>>4)*4+reg
                float av = acc[mt][2 * p][jj] + bb1;
                float gv = acc[mt][2 * p + 1][jj] + bb3;
                float hv = av * gv / (1.f + __expf(-gv));    // silu(g)*a
                int ent = rowtok[mrow];
                hbuf[(size_t)((ent >> 2) * NSLOT + (ent & 3)) * H_DIM + h] = f2b(hv);
            }
        }
    }
}

// ---------------- expert down: [h rows] x [w2^T], K = H ----------------
__global__ __launch_bounds__(256) void expert_down_kernel(
        const unsigned short* __restrict__ hbuf, const unsigned short* __restrict__ wt2t,
        const float* __restrict__ b2, const float* __restrict__ cw,
        const int* __restrict__ counts, const int* __restrict__ lists,
        float* __restrict__ outslot) {
    const int e = blockIdx.z;
    const int cnt = counts[e];
    const int m0 = blockIdx.x * BM;
    if (m0 >= cnt) return;
    const int c0 = blockIdx.y * BN;
    const int t = threadIdx.x;
    const int lane = t & 63, w = t >> 6;
    const int ln15 = lane & 15, lg = lane >> 4;
    const int wr = w >> 1, wc = w & 1;

    __shared__ __align__(16) unsigned short As[BM * BK];
    __shared__ __align__(16) unsigned short Bs[BN * BK];
    __shared__ int rowtok[BM];

    if (t < BM) {
        int r = m0 + t;
        rowtok[t] = lists[e * N_TOK + (r < cnt ? r : cnt - 1)];
    }
    __syncthreads();

    const unsigned short* wtb = wt2t + (size_t)e * C_DIM * H_DIM;
    const unsigned short* asrc[4];
    const unsigned short* bsrc[4];
#pragma unroll
    for (int i = 0; i < 4; i++) {
        int c = i * 256 + w * 64 + lane;
        int row = c >> 3, slot = c & 7, kc = slot ^ (row & 7);
        int ent = rowtok[row];
        asrc[i] = hbuf + (size_t)((ent >> 2) * NSLOT + (ent & 3)) * H_DIM + kc * 8;
        bsrc[i] = wtb + (size_t)(c0 + row) * H_DIM + kc * 8;
    }

    f32x4 acc[4][4];
#pragma unroll
    for (int a = 0; a < 4; a++)
#pragma unroll
        for (int b = 0; b < 4; b++) acc[a][b] = (f32x4){0.f, 0.f, 0.f, 0.f};

    const int swz = ln15 & 7;
    for (int kt = 0; kt < H_DIM / BK; kt++) {
#pragma unroll
        for (int i = 0; i < 4; i++) {
            gload16(asrc[i], As + (i * 256 + w * 64) * 8);
            gload16(bsrc[i], Bs + (i * 256 + w * 64) * 8);
            asrc[i] += BK; bsrc[i] += BK;
        }
        __syncthreads();
#pragma unroll
        for (int j = 0; j < 2; j++) {
            FragU af[4], bf[4];
#pragma unroll
            for (int mt = 0; mt < 4; mt++) {
                int row = wr * 64 + mt * 16 + ln15;
                int slot = (j * 4 + lg) ^ swz;
                af[mt].v = *(const bf16x8*)(As + row * BK + slot * 8);
            }
#pragma unroll
            for (int nt = 0; nt < 4; nt++) {
                int row = wc * 64 + nt * 16 + ln15;
                int slot = (j * 4 + lg) ^ swz;
                bf[nt].v = *(const bf16x8*)(Bs + row * BK + slot * 8);
            }
#pragma unroll
            for (int mt = 0; mt < 4; mt++)
#pragma unroll
                for (int nt = 0; nt < 4; nt++)
                    acc[mt][nt] = __builtin_amdgcn_mfma_f32_16x16x32_bf16(
                        af[mt].v, bf[nt].v, acc[mt][nt], 0, 0, 0);
        }
        __syncthreads();
    }

#pragma unroll
    for (int nt = 0; nt < 4; nt++) {
        int col = c0 + wc * 64 + nt * 16 + ln15;
        float bb = b2[e * C_DIM + col];
#pragma unroll
        for (int mt = 0; mt < 4; mt++) {
#pragma unroll
            for (int jj = 0; jj < 4; jj++) {
                int mrow = wr * 64 + mt * 16 + lg * 4 + jj;
                int ent = rowtok[mrow];
                int tok = ent >> 2, slot = ent & 3;
                float cwv = cw[tok * NE + e];
                outslot[(size_t)(tok * NSLOT + slot) * C_DIM + col] =
                    cwv * (acc[mt][nt][jj] + bb);
            }
        }
    }
}

__global__ __launch_bounds__(256) void reduce_kernel(
        const float* __restrict__ os, float* __restrict__ out) {
    int i = blockIdx.x * 256 + threadIdx.x;   // over N*C/4
    int n = i >> 8;
    int c = (i & 255) * 4;
    const float4 s0 = *(const float4*)(os + ((size_t)n * NSLOT + 0) * C_DIM + c);
    const float4 s1 = *(const float4*)(os + ((size_t)n * NSLOT + 1) * C_DIM + c);
    const float4 s2 = *(const float4*)(os + ((size_t)n * NSLOT + 2) * C_DIM + c);
    float4 r;
    r.x = s0.x + s1.x + s2.x; r.y = s0.y + s1.y + s2.y;
    r.z = s0.z + s1.z + s2.z; r.w = s0.w + s1.w + s2.w;
    *(float4*)(out + (size_t)n * C_DIM + c) = r;
}

__global__ void loss_kernel(const float* __restrict__ cw, const int* __restrict__ counts,
                            float* __restrict__ out) {
    int lane = threadIdx.x;
    float ss[NE];
#pragma unroll
    for (int e = 0; e < NE; e++) ss[e] = 0.f;
    for (int n = lane; n < N_TOK; n += 64) {
#pragma unroll
        for (int e = 0; e < NE; e++) ss[e] += cw[n * NE + e];
    }
#pragma unroll
    for (int e = 0; e < NE; e++) {
#pragma unroll
        for (int off = 32; off >= 1; off >>= 1) ss[e] += __shfl_xor(ss[e], off, 64);
    }
    if (lane == 0) {
        float bal = 0.f;
        const float fac = (float)NE / (3.f * (float)N_TOK * (float)N_TOK);
#pragma unroll
        for (int e = 0; e < NE; e++) bal += fac * (float)counts[e] * ss[e];
        out[(size_t)N_TOK * C_DIM] = bal;
    }
}

extern "C" void kernel_launch(void* const* d_in, const int* in_sizes, int n_in,
                              void* d_out, int out_size, void* d_ws, size_t ws_size,
                              hipStream_t stream) {
    const float* x  = (const float*)d_in[0];
    const float* gw = (const float*)d_in[1];
    const float* gb = (const float*)d_in[2];
    const float* w1 = (const float*)d_in[3];
    const float* b1 = (const float*)d_in[4];
    const float* w2 = (const float*)d_in[5];
    const float* b2 = (const float*)d_in[6];
    const float* w3 = (const float*)d_in[7];
    const float* b3 = (const float*)d_in[8];
    float* out = (float*)d_out;
    char* ws = (char*)d_ws;
    int*            counts = (int*)(ws + WS_COUNTS);
    float*          cw     = (float*)(ws + WS_CW);
    int*            lists  = (int*)(ws + WS_LISTS);
    unsigned short* xb     = (unsigned short*)(ws + WS_XB);
    unsigned short* hbuf   = (unsigned short*)(ws + WS_HBUF);
    float*          oslot  = (float*)(ws + WS_OUTSLOT);
    unsigned short* wt13   = (unsigned short*)(ws + WS_WT13);
    unsigned short* wt2t   = (unsigned short*)(ws + WS_WT2T);

    hipLaunchKernelGGL(zero_kernel, dim3(1), dim3(64), 0, stream, counts);
    hipLaunchKernelGGL(gate_kernel, dim3(N_TOK / 4), dim3(256), 0, stream,
                       x, gw, gb, cw, xb, counts, lists);
    // weight prepass: w1/w3 -> wt13 [E][2H][C] (16-row interleave), w2 -> wt2t [E][C][H]
    hipLaunchKernelGGL(tcast_kernel, dim3(C_DIM / 64, H_DIM / 64, NE), dim3(256), 0, stream,
                       w1, wt13, C_DIM, H_DIM, 2 * H_DIM, 5, 0);
    hipLaunchKernelGGL(tcast_kernel, dim3(C_DIM / 64, H_DIM / 64, NE), dim3(256), 0, stream,
                       w3, wt13, C_DIM, H_DIM, 2 * H_DIM, 5, 16);
    hipLaunchKernelGGL(tcast_kernel, dim3(H_DIM / 64, C_DIM / 64, NE), dim3(256), 0, stream,
                       w2, wt2t, H_DIM, C_DIM, C_DIM, 4, 0);
    hipLaunchKernelGGL(expert_up_kernel, dim3(N_TOK / BM, 2 * H_DIM / BN, NE), dim3(256), 0, stream,
                       xb, wt13, b1, b3, counts, lists, hbuf);
    hipLaunchKernelGGL(expert_down_kernel, dim3(N_TOK / BM, C_DIM / BN, NE), dim3(256), 0, stream,
                       hbuf, wt2t, b2, cw, counts, lists, oslot);
    hipLaunchKernelGGL(reduce_kernel, dim3((N_TOK * C_DIM / 4) / 256), dim3(256), 0, stream,
                       oslot, out);
    hipLaunchKernelGGL(loss_kernel, dim3(1), dim3(64), 0, stream, cw, counts, out);
}

// Round 3
// 390.560 us; speedup vs baseline: 1.9785x; 1.0262x over previous
//
#include <hip/hip_runtime.h>
#include <stdint.h>

#define N_TOK 2048
#define C_DIM 1024
#define H_DIM 2048
#define NE 8
#define NSLOT 3

#define BM 128
#define BN 128
#define BK 64

// ws layout (bytes); every section multiple of 256
#define WS_COUNTS   0
#define WS_CW       256
#define WS_LISTS    (WS_CW + N_TOK*NE*4)
#define WS_XB       (WS_LISTS + NE*N_TOK*4)
#define WS_HBUF     (WS_XB + (size_t)N_TOK*C_DIM*2)
#define WS_OUTSLOT  (WS_HBUF + (size_t)N_TOK*NSLOT*H_DIM*2)
#define WS_WT13     (WS_OUTSLOT + (size_t)N_TOK*NSLOT*C_DIM*4)
#define WS_WT2T     (WS_WT13 + (size_t)NE*2*H_DIM*C_DIM*2)
// total ≈ 154 MB

typedef short bf16x8 __attribute__((ext_vector_type(8)));
typedef float f32x4 __attribute__((ext_vector_type(4)));

union FragU { bf16x8 v; uint2 u2[2]; };

__device__ __forceinline__ unsigned short f2b(float f) {
    union { float f; uint32_t u; } v; v.f = f;
    return (unsigned short)((v.u + 0x7fffu + ((v.u >> 16) & 1u)) >> 16); // RNE
}

// async global->LDS, 16B per lane; lds dest is wave-uniform base + lane*16
__device__ __forceinline__ void gload16(const unsigned short* g, unsigned short* l) {
    __builtin_amdgcn_global_load_lds(
        (const __attribute__((address_space(1))) unsigned int*)g,
        (__attribute__((address_space(3))) unsigned int*)l, 16, 0, 0);
}

__global__ void zero_kernel(int* counts) {
    if (threadIdx.x < NE) counts[threadIdx.x] = 0;
}

// ---------------- gating: one wave per token ----------------
__global__ __launch_bounds__(256) void gate_kernel(
        const float* __restrict__ x, const float* __restrict__ gw,
        const float* __restrict__ gb, float* __restrict__ cw,
        unsigned short* __restrict__ xb, int* __restrict__ counts,
        int* __restrict__ lists) {
    int n = (blockIdx.x * 256 + threadIdx.x) >> 6;
    int lane = threadIdx.x & 63;
    if (n >= N_TOK) return;
    float acc[NE];
#pragma unroll
    for (int e = 0; e < NE; e++) acc[e] = 0.f;
    for (int c = lane; c < C_DIM; c += 64) {
        float xv = x[n * C_DIM + c];
        xb[n * C_DIM + c] = f2b(xv);
        const float* g = gw + c * NE;
#pragma unroll
        for (int e = 0; e < NE; e++) acc[e] += xv * g[e];
    }
#pragma unroll
    for (int e = 0; e < NE; e++) {
#pragma unroll
        for (int off = 32; off >= 1; off >>= 1) acc[e] += __shfl_xor(acc[e], off, 64);
        acc[e] += gb[e];
    }
    float m = acc[0];
#pragma unroll
    for (int e = 1; e < NE; e++) m = fmaxf(m, acc[e]);
    float s = 0.f, sc[NE];
#pragma unroll
    for (int e = 0; e < NE; e++) { sc[e] = __expf(acc[e] - m); s += sc[e]; }
    float inv = 1.f / s;
#pragma unroll
    for (int e = 0; e < NE; e++) sc[e] *= inv;
    // top-2 of routed experts 1..7; ties -> lower index (matches lax.top_k)
    int i1 = 1; float v1 = sc[1];
#pragma unroll
    for (int e = 2; e < NE; e++) if (sc[e] > v1) { v1 = sc[e]; i1 = e; }
    int i2 = 0; float v2 = -1.f;
#pragma unroll
    for (int e = 1; e < NE; e++) if (e != i1 && sc[e] > v2) { v2 = sc[e]; i2 = e; }
    if (lane < NE) {
        float v = 0.f;
        if (lane == 0) v = sc[0];
        else if (lane == i1) v = v1;
        else if (lane == i2) v = v2;
        cw[n * NE + lane] = v;
    }
    if (lane == 0) {  // entry = token*4 + slot
        int p0 = atomicAdd(&counts[0], 1);  lists[p0] = n * 4 + 0;
        int p1 = atomicAdd(&counts[i1], 1); lists[i1 * N_TOK + p1] = n * 4 + 1;
        int p2 = atomicAdd(&counts[i2], 1); lists[i2 * N_TOK + p2] = n * 4 + 2;
    }
}

// ---------- weight prepass: transpose + cast to bf16 B^T layout ----------
// src [E][K][N] fp32 -> dst [E][Nr][K] bf16, dest row r = ((n>>4)<<shift)+(n&15)+off
// z encodes op*: op0 w1->wt13(shift5,off0), op1 w3->wt13(shift5,off16), op2 w2->wt2t(shift4,off0)
__global__ __launch_bounds__(256) void tcast_all_kernel(
        const float* __restrict__ w1, const float* __restrict__ w3,
        const float* __restrict__ w2, unsigned short* __restrict__ wt13,
        unsigned short* __restrict__ wt2t) {
    int op = blockIdx.z % 3, e = blockIdx.z / 3;
    const float* src; unsigned short* dst;
    int K, N, Nr, shift, off, k0, n0;
    if (op < 2) {
        src = op ? w3 : w1; dst = wt13;
        K = C_DIM; N = H_DIM; Nr = 2 * H_DIM; shift = 5; off = op ? 16 : 0;
        k0 = blockIdx.x * 64; n0 = blockIdx.y * 64;
    } else {
        src = w2; dst = wt2t;
        K = H_DIM; N = C_DIM; Nr = C_DIM; shift = 4; off = 0;
        k0 = blockIdx.y * 64; n0 = blockIdx.x * 64;   // swap: x covers N=1024, y covers K=2048
    }
    __shared__ unsigned short tile[64][72];
    const float* s = src + ((size_t)e * K + k0) * N + n0;
    int tr = threadIdx.x >> 4, tc = (threadIdx.x & 15) * 4;
#pragma unroll
    for (int i = 0; i < 4; i++) {
        float4 v = *(const float4*)(s + (size_t)(tr + i * 16) * N + tc);
        tile[tr + i * 16][tc + 0] = f2b(v.x);
        tile[tr + i * 16][tc + 1] = f2b(v.y);
        tile[tr + i * 16][tc + 2] = f2b(v.z);
        tile[tr + i * 16][tc + 3] = f2b(v.w);
    }
    __syncthreads();
    int hl = threadIdx.x >> 3, kl = (threadIdx.x & 7) * 8;
#pragma unroll
    for (int i = 0; i < 2; i++) {
        int hloc = hl + i * 32;
        int n = n0 + hloc;
        int r = ((n >> 4) << shift) + (n & 15) + off;
        unsigned short tmp[8];
#pragma unroll
        for (int q = 0; q < 8; q++) tmp[q] = tile[kl + q][hloc];
        *(uint4*)(dst + ((size_t)e * Nr + r) * K + k0 + kl) = *(uint4*)tmp;
    }
}

// STAGE: issue 8 async 16B global->LDS loads (4 A-chunks + 4 B-chunks per lane)
#define STAGE(nA, nB, koff) do {                                          \
    _Pragma("unroll")                                                     \
    for (int i_ = 0; i_ < 4; i_++) {                                      \
        gload16(asrc[i_] + (koff), (nA) + (i_ * 256 + w * 64) * 8);       \
        gload16(bsrc[i_] + (koff), (nB) + (i_ * 256 + w * 64) * 8);       \
    }                                                                     \
} while (0)

// COMPUTE: 8 ds_read_b128 + 32 MFMA on one 128x128x64 tile
#define COMPUTE(cA, cB) do {                                              \
    _Pragma("unroll")                                                     \
    for (int j_ = 0; j_ < 2; j_++) {                                      \
        FragU af[4], bf[4];                                               \
        _Pragma("unroll")                                                 \
        for (int mt = 0; mt < 4; mt++) {                                  \
            int row = wr * 64 + mt * 16 + ln15;                           \
            int slot = (j_ * 4 + lg) ^ swz;                               \
            af[mt].v = *(const bf16x8*)((cA) + row * BK + slot * 8);      \
        }                                                                 \
        _Pragma("unroll")                                                 \
        for (int nt = 0; nt < 4; nt++) {                                  \
            int row = wc * 64 + nt * 16 + ln15;                           \
            int slot = (j_ * 4 + lg) ^ swz;                               \
            bf[nt].v = *(const bf16x8*)((cB) + row * BK + slot * 8);      \
        }                                                                 \
        _Pragma("unroll")                                                 \
        for (int mt = 0; mt < 4; mt++)                                    \
            _Pragma("unroll")                                             \
            for (int nt = 0; nt < 4; nt++)                                \
                acc[mt][nt] = __builtin_amdgcn_mfma_f32_16x16x32_bf16(    \
                    af[mt].v, bf[nt].v, acc[mt][nt], 0, 0, 0);            \
    }                                                                     \
} while (0)

// 2-phase pipelined K-loop: stage tile t+1 BEFORE computing tile t; counted
// vmcnt(8) lets the 8 just-issued loads stay in flight across the barrier
// (raw s_barrier: __syncthreads would drain vmcnt(0) and kill the overlap).
#define KLOOP(NK) do {                                                    \
    STAGE(As0, Bs0, 0);                                                   \
    for (int kt = 0; kt < (NK); kt += 2) {                                \
        STAGE(As1, Bs1, (kt + 1) * BK);                                   \
        asm volatile("s_waitcnt vmcnt(8)" ::: "memory");                  \
        __builtin_amdgcn_s_barrier();                                     \
        COMPUTE(As0, Bs0);                                                \
        __builtin_amdgcn_s_barrier();                                     \
        if (kt + 2 < (NK)) {                                              \
            STAGE(As0, Bs0, (kt + 2) * BK);                               \
            asm volatile("s_waitcnt vmcnt(8)" ::: "memory");              \
        } else {                                                          \
            asm volatile("s_waitcnt vmcnt(0)" ::: "memory");              \
        }                                                                 \
        __builtin_amdgcn_s_barrier();                                     \
        COMPUTE(As1, Bs1);                                                \
        __builtin_amdgcn_s_barrier();                                     \
    }                                                                     \
} while (0)

// ---------------- expert up: [tokens]x[w1|w3 interleaved] ----------------
// A = gathered xb rows (M=128), B = wt13 rows (N=128 combined), K = C.
// LDS chunk swizzle: chunk c -> row=c>>3, slot=c&7, holds k-chunk kc=slot^(row&7).
__global__ __launch_bounds__(256) void expert_up_kernel(
        const unsigned short* __restrict__ xb, const unsigned short* __restrict__ wt13,
        const float* __restrict__ b1, const float* __restrict__ b3,
        const int* __restrict__ counts, const int* __restrict__ lists,
        unsigned short* __restrict__ hbuf) {
    const int e = blockIdx.z;
    const int cnt = counts[e];
    const int m0 = blockIdx.x * BM;
    if (m0 >= cnt) return;
    const int n0 = blockIdx.y * BN;
    const int t = threadIdx.x;
    const int lane = t & 63, w = t >> 6;
    const int ln15 = lane & 15, lg = lane >> 4;
    const int wr = w >> 1, wc = w & 1;

    __shared__ __align__(16) unsigned short As0[BM * BK], Bs0[BN * BK];
    __shared__ __align__(16) unsigned short As1[BM * BK], Bs1[BN * BK];
    __shared__ int rowtok[BM];

    if (t < BM) {
        int r = m0 + t;  // tail rows duplicate last valid token (benign dup writes)
        rowtok[t] = lists[e * N_TOK + (r < cnt ? r : cnt - 1)];
    }
    __syncthreads();

    const unsigned short* wtb = wt13 + (size_t)e * (2 * H_DIM) * C_DIM;
    const unsigned short* asrc[4];
    const unsigned short* bsrc[4];
#pragma unroll
    for (int i = 0; i < 4; i++) {
        int c = i * 256 + w * 64 + lane;         // LDS chunk index (16B units)
        int row = c >> 3, slot = c & 7, kc = slot ^ (row & 7);
        asrc[i] = xb + (size_t)(rowtok[row] >> 2) * C_DIM + kc * 8;
        bsrc[i] = wtb + (size_t)(n0 + row) * C_DIM + kc * 8;
    }

    f32x4 acc[4][4];
#pragma unroll
    for (int a = 0; a < 4; a++)
#pragma unroll
        for (int b = 0; b < 4; b++) acc[a][b] = (f32x4){0.f, 0.f, 0.f, 0.f};

    const int swz = ln15 & 7;
    KLOOP(C_DIM / BK);

    // epilogue: nt pairs (0,1),(2,3) are (a,g) for the same h column
#pragma unroll
    for (int p = 0; p < 2; p++) {
        int h = ((n0 + wc * 64 + p * 32) >> 5) * 16 + ln15;
        float bb1 = b1[e * H_DIM + h], bb3 = b3[e * H_DIM + h];
#pragma unroll
        for (int mt = 0; mt < 4; mt++) {
#pragma unroll
            for (int jj = 0; jj < 4; jj++) {
                int mrow = wr * 64 + mt * 16 + lg * 4 + jj;  // C/D: row=(lane>>4)*4+reg
                float av = acc[mt][2 * p][jj] + bb1;
                float gv = acc[mt][2 * p + 1][jj] + bb3;
                float hv = av * gv / (1.f + __expf(-gv));    // silu(g)*a
                int ent = rowtok[mrow];
                hbuf[(size_t)((ent >> 2) * NSLOT + (ent & 3)) * H_DIM + h] = f2b(hv);
            }
        }
    }
}

// ---------------- expert down: [h rows] x [w2^T], K = H ----------------
__global__ __launch_bounds__(256) void expert_down_kernel(
        const unsigned short* __restrict__ hbuf, const unsigned short* __restrict__ wt2t,
        const float* __restrict__ b2, const float* __restrict__ cw,
        const int* __restrict__ counts, const int* __restrict__ lists,
        float* __restrict__ outslot) {
    const int e = blockIdx.z;
    const int cnt = counts[e];
    const int m0 = blockIdx.x * BM;
    if (m0 >= cnt) return;
    const int c0 = blockIdx.y * BN;
    const int t = threadIdx.x;
    const int lane = t & 63, w = t >> 6;
    const int ln15 = lane & 15, lg = lane >> 4;
    const int wr = w >> 1, wc = w & 1;

    __shared__ __align__(16) unsigned short As0[BM * BK], Bs0[BN * BK];
    __shared__ __align__(16) unsigned short As1[BM * BK], Bs1[BN * BK];
    __shared__ int rowtok[BM];

    if (t < BM) {
        int r = m0 + t;
        rowtok[t] = lists[e * N_TOK + (r < cnt ? r : cnt - 1)];
    }
    __syncthreads();

    const unsigned short* wtb = wt2t + (size_t)e * C_DIM * H_DIM;
    const unsigned short* asrc[4];
    const unsigned short* bsrc[4];
#pragma unroll
    for (int i = 0; i < 4; i++) {
        int c = i * 256 + w * 64 + lane;
        int row = c >> 3, slot = c & 7, kc = slot ^ (row & 7);
        int ent = rowtok[row];
        asrc[i] = hbuf + (size_t)((ent >> 2) * NSLOT + (ent & 3)) * H_DIM + kc * 8;
        bsrc[i] = wtb + (size_t)(c0 + row) * H_DIM + kc * 8;
    }

    f32x4 acc[4][4];
#pragma unroll
    for (int a = 0; a < 4; a++)
#pragma unroll
        for (int b = 0; b < 4; b++) acc[a][b] = (f32x4){0.f, 0.f, 0.f, 0.f};

    const int swz = ln15 & 7;
    KLOOP(H_DIM / BK);

#pragma unroll
    for (int nt = 0; nt < 4; nt++) {
        int col = c0 + wc * 64 + nt * 16 + ln15;
        float bb = b2[e * C_DIM + col];
#pragma unroll
        for (int mt = 0; mt < 4; mt++) {
#pragma unroll
            for (int jj = 0; jj < 4; jj++) {
                int mrow = wr * 64 + mt * 16 + lg * 4 + jj;
                int ent = rowtok[mrow];
                int tok = ent >> 2, slot = ent & 3;
                float cwv = cw[tok * NE + e];
                outslot[(size_t)(tok * NSLOT + slot) * C_DIM + col] =
                    cwv * (acc[mt][nt][jj] + bb);
            }
        }
    }
}

__global__ __launch_bounds__(256) void reduce_kernel(
        const float* __restrict__ os, float* __restrict__ out) {
    int i = blockIdx.x * 256 + threadIdx.x;   // over N*C/4
    int n = i >> 8;
    int c = (i & 255) * 4;
    const float4 s0 = *(const float4*)(os + ((size_t)n * NSLOT + 0) * C_DIM + c);
    const float4 s1 = *(const float4*)(os + ((size_t)n * NSLOT + 1) * C_DIM + c);
    const float4 s2 = *(const float4*)(os + ((size_t)n * NSLOT + 2) * C_DIM + c);
    float4 r;
    r.x = s0.x + s1.x + s2.x; r.y = s0.y + s1.y + s2.y;
    r.z = s0.z + s1.z + s2.z; r.w = s0.w + s1.w + s2.w;
    *(float4*)(out + (size_t)n * C_DIM + c) = r;
}

__global__ void loss_kernel(const float* __restrict__ cw, const int* __restrict__ counts,
                            float* __restrict__ out) {
    int lane = threadIdx.x;
    float ss[NE];
#pragma unroll
    for (int e = 0; e < NE; e++) ss[e] = 0.f;
    for (int n = lane; n < N_TOK; n += 64) {
#pragma unroll
        for (int e = 0; e < NE; e++) ss[e] += cw[n * NE + e];
    }
#pragma unroll
    for (int e = 0; e < NE; e++) {
#pragma unroll
        for (int off = 32; off >= 1; off >>= 1) ss[e] += __shfl_xor(ss[e], off, 64);
    }
    if (lane == 0) {
        float bal = 0.f;
        const float fac = (float)NE / (3.f * (float)N_TOK * (float)N_TOK);
#pragma unroll
        for (int e = 0; e < NE; e++) bal += fac * (float)counts[e] * ss[e];
        out[(size_t)N_TOK * C_DIM] = bal;
    }
}

extern "C" void kernel_launch(void* const* d_in, const int* in_sizes, int n_in,
                              void* d_out, int out_size, void* d_ws, size_t ws_size,
                              hipStream_t stream) {
    const float* x  = (const float*)d_in[0];
    const float* gw = (const float*)d_in[1];
    const float* gb = (const float*)d_in[2];
    const float* w1 = (const float*)d_in[3];
    const float* b1 = (const float*)d_in[4];
    const float* w2 = (const float*)d_in[5];
    const float* b2 = (const float*)d_in[6];
    const float* w3 = (const float*)d_in[7];
    const float* b3 = (const float*)d_in[8];
    float* out = (float*)d_out;
    char* ws = (char*)d_ws;
    int*            counts = (int*)(ws + WS_COUNTS);
    float*          cw     = (float*)(ws + WS_CW);
    int*            lists  = (int*)(ws + WS_LISTS);
    unsigned short* xb     = (unsigned short*)(ws + WS_XB);
    unsigned short* hbuf   = (unsigned short*)(ws + WS_HBUF);
    float*          oslot  = (float*)(ws + WS_OUTSLOT);
    unsigned short* wt13   = (unsigned short*)(ws + WS_WT13);
    unsigned short* wt2t   = (unsigned short*)(ws + WS_WT2T);

    hipLaunchKernelGGL(zero_kernel, dim3(1), dim3(64), 0, stream, counts);
    hipLaunchKernelGGL(gate_kernel, dim3(N_TOK / 4), dim3(256), 0, stream,
                       x, gw, gb, cw, xb, counts, lists);
    hipLaunchKernelGGL(tcast_all_kernel, dim3(C_DIM / 64, H_DIM / 64, NE * 3), dim3(256), 0, stream,
                       w1, w3, w2, wt13, wt2t);
    hipLaunchKernelGGL(expert_up_kernel, dim3(N_TOK / BM, 2 * H_DIM / BN, NE), dim3(256), 0, stream,
                       xb, wt13, b1, b3, counts, lists, hbuf);
    hipLaunchKernelGGL(expert_down_kernel, dim3(N_TOK / BM, C_DIM / BN, NE), dim3(256), 0, stream,
                       hbuf, wt2t, b2, cw, counts, lists, oslot);
    hipLaunchKernelGGL(reduce_kernel, dim3((N_TOK * C_DIM / 4) / 256), dim3(256), 0, stream,
                       oslot, out);
    hipLaunchKernelGGL(loss_kernel, dim3(1), dim3(64), 0, stream, cw, counts, out);
}

// Round 4
// 335.411 us; speedup vs baseline: 2.3038x; 1.1644x over previous
//
#include <hip/hip_runtime.h>
#include <stdint.h>

#define N_TOK 2048
#define C_DIM 1024
#define H_DIM 2048
#define NE 8
#define NSLOT 3

#define BM 128
#define BN 128
#define BK 64
#define PGRID 512   // persistent blocks: 256 CU x 2 resident (66KB LDS)

// ws layout (bytes); every section multiple of 256
#define WS_COUNTS   0
#define WS_PLAN     256
#define WS_CW       (WS_PLAN + 1024)
#define WS_LISTS    (WS_CW + N_TOK*NE*4)
#define WS_XB       (WS_LISTS + NE*N_TOK*4)
#define WS_HBUF     (WS_XB + (size_t)N_TOK*C_DIM*2)
#define WS_OUTSLOT  (WS_HBUF + (size_t)N_TOK*NSLOT*H_DIM*2)
#define WS_WT13     (WS_OUTSLOT + (size_t)N_TOK*NSLOT*C_DIM*4)
#define WS_WT2T     (WS_WT13 + (size_t)NE*2*H_DIM*C_DIM*2)
// total ≈ 154 MB

typedef short bf16x8 __attribute__((ext_vector_type(8)));
typedef float f32x4 __attribute__((ext_vector_type(4)));

union FragU { bf16x8 v; uint2 u2[2]; };

__device__ __forceinline__ unsigned short f2b(float f) {
    union { float f; uint32_t u; } v; v.f = f;
    return (unsigned short)((v.u + 0x7fffu + ((v.u >> 16) & 1u)) >> 16); // RNE
}

// async global->LDS, 16B per lane; lds dest is wave-uniform base + lane*16
__device__ __forceinline__ void gload16(const unsigned short* g, unsigned short* l) {
    __builtin_amdgcn_global_load_lds(
        (const __attribute__((address_space(1))) unsigned int*)g,
        (__attribute__((address_space(3))) unsigned int*)l, 16, 0, 0);
}

__global__ void zero_kernel(int* counts) {
    if (threadIdx.x < NE) counts[threadIdx.x] = 0;
}

// ---------------- gating: one wave per token ----------------
__global__ __launch_bounds__(256) void gate_kernel(
        const float* __restrict__ x, const float* __restrict__ gw,
        const float* __restrict__ gb, float* __restrict__ cw,
        unsigned short* __restrict__ xb, int* __restrict__ counts,
        int* __restrict__ lists) {
    int n = (blockIdx.x * 256 + threadIdx.x) >> 6;
    int lane = threadIdx.x & 63;
    if (n >= N_TOK) return;
    float acc[NE];
#pragma unroll
    for (int e = 0; e < NE; e++) acc[e] = 0.f;
    for (int c = lane; c < C_DIM; c += 64) {
        float xv = x[n * C_DIM + c];
        xb[n * C_DIM + c] = f2b(xv);
        const float* g = gw + c * NE;
#pragma unroll
        for (int e = 0; e < NE; e++) acc[e] += xv * g[e];
    }
#pragma unroll
    for (int e = 0; e < NE; e++) {
#pragma unroll
        for (int off = 32; off >= 1; off >>= 1) acc[e] += __shfl_xor(acc[e], off, 64);
        acc[e] += gb[e];
    }
    float m = acc[0];
#pragma unroll
    for (int e = 1; e < NE; e++) m = fmaxf(m, acc[e]);
    float s = 0.f, sc[NE];
#pragma unroll
    for (int e = 0; e < NE; e++) { sc[e] = __expf(acc[e] - m); s += sc[e]; }
    float inv = 1.f / s;
#pragma unroll
    for (int e = 0; e < NE; e++) sc[e] *= inv;
    // top-2 of routed experts 1..7; ties -> lower index (matches lax.top_k)
    int i1 = 1; float v1 = sc[1];
#pragma unroll
    for (int e = 2; e < NE; e++) if (sc[e] > v1) { v1 = sc[e]; i1 = e; }
    int i2 = 0; float v2 = -1.f;
#pragma unroll
    for (int e = 1; e < NE; e++) if (e != i1 && sc[e] > v2) { v2 = sc[e]; i2 = e; }
    if (lane < NE) {
        float v = 0.f;
        if (lane == 0) v = sc[0];
        else if (lane == i1) v = v1;
        else if (lane == i2) v = v2;
        cw[n * NE + lane] = v;
    }
    if (lane == 0) {  // entry = token*4 + slot
        int p0 = atomicAdd(&counts[0], 1);  lists[p0] = n * 4 + 0;
        int p1 = atomicAdd(&counts[i1], 1); lists[i1 * N_TOK + p1] = n * 4 + 1;
        int p2 = atomicAdd(&counts[i2], 1); lists[i2 * N_TOK + p2] = n * 4 + 2;
    }
}

// ---------------- plan: compacted (expert, m-block) work list ----------------
__global__ void plan_kernel(const int* __restrict__ counts, int* __restrict__ plan) {
    if (threadIdx.x == 0) {
        int p = 0;
        for (int e = 0; e < NE; e++) {
            int nb = (counts[e] + BM - 1) / BM;
            for (int m = 0; m < nb; m++) plan[1 + p++] = (e << 8) | m;
        }
        plan[0] = p;
    }
}

// ---------- weight prepass: transpose + cast to bf16 B^T layout ----------
// src [E][K][N] fp32 -> dst [E][Nr][K] bf16, dest row r = ((n>>4)<<shift)+(n&15)+off
// z encodes op*: op0 w1->wt13(shift5,off0), op1 w3->wt13(shift5,off16), op2 w2->wt2t(shift4,off0)
__global__ __launch_bounds__(256) void tcast_all_kernel(
        const float* __restrict__ w1, const float* __restrict__ w3,
        const float* __restrict__ w2, unsigned short* __restrict__ wt13,
        unsigned short* __restrict__ wt2t) {
    int op = blockIdx.z % 3, e = blockIdx.z / 3;
    const float* src; unsigned short* dst;
    int K, N, Nr, shift, off, k0, n0;
    if (op < 2) {
        src = op ? w3 : w1; dst = wt13;
        K = C_DIM; N = H_DIM; Nr = 2 * H_DIM; shift = 5; off = op ? 16 : 0;
        k0 = blockIdx.x * 64; n0 = blockIdx.y * 64;
    } else {
        src = w2; dst = wt2t;
        K = H_DIM; N = C_DIM; Nr = C_DIM; shift = 4; off = 0;
        k0 = blockIdx.y * 64; n0 = blockIdx.x * 64;   // swap: x covers N=1024, y covers K=2048
    }
    __shared__ unsigned short tile[64][72];
    const float* s = src + ((size_t)e * K + k0) * N + n0;
    int tr = threadIdx.x >> 4, tc = (threadIdx.x & 15) * 4;
#pragma unroll
    for (int i = 0; i < 4; i++) {
        float4 v = *(const float4*)(s + (size_t)(tr + i * 16) * N + tc);
        tile[tr + i * 16][tc + 0] = f2b(v.x);
        tile[tr + i * 16][tc + 1] = f2b(v.y);
        tile[tr + i * 16][tc + 2] = f2b(v.z);
        tile[tr + i * 16][tc + 3] = f2b(v.w);
    }
    __syncthreads();
    int hl = threadIdx.x >> 3, kl = (threadIdx.x & 7) * 8;
#pragma unroll
    for (int i = 0; i < 2; i++) {
        int hloc = hl + i * 32;
        int n = n0 + hloc;
        int r = ((n >> 4) << shift) + (n & 15) + off;
        unsigned short tmp[8];
#pragma unroll
        for (int q = 0; q < 8; q++) tmp[q] = tile[kl + q][hloc];
        *(uint4*)(dst + ((size_t)e * Nr + r) * K + k0 + kl) = *(uint4*)tmp;
    }
}

// STAGE: issue 8 async 16B global->LDS loads (4 A-chunks + 4 B-chunks per lane)
#define STAGE(nA, nB, koff) do {                                          \
    _Pragma("unroll")                                                     \
    for (int i_ = 0; i_ < 4; i_++) {                                      \
        gload16(asrc[i_] + (koff), (nA) + (i_ * 256 + w * 64) * 8);       \
        gload16(bsrc[i_] + (koff), (nB) + (i_ * 256 + w * 64) * 8);       \
    }                                                                     \
} while (0)

// COMPUTE: 8 ds_read_b128 + 32 MFMA on one 128x128x64 tile
#define COMPUTE(cA, cB) do {                                              \
    _Pragma("unroll")                                                     \
    for (int j_ = 0; j_ < 2; j_++) {                                      \
        FragU af[4], bf[4];                                               \
        _Pragma("unroll")                                                 \
        for (int mt = 0; mt < 4; mt++) {                                  \
            int row = wr * 64 + mt * 16 + ln15;                           \
            int slot = (j_ * 4 + lg) ^ swz;                               \
            af[mt].v = *(const bf16x8*)((cA) + row * BK + slot * 8);      \
        }                                                                 \
        _Pragma("unroll")                                                 \
        for (int nt = 0; nt < 4; nt++) {                                  \
            int row = wc * 64 + nt * 16 + ln15;                           \
            int slot = (j_ * 4 + lg) ^ swz;                               \
            bf[nt].v = *(const bf16x8*)((cB) + row * BK + slot * 8);      \
        }                                                                 \
        _Pragma("unroll")                                                 \
        for (int mt = 0; mt < 4; mt++)                                    \
            _Pragma("unroll")                                             \
            for (int nt = 0; nt < 4; nt++)                                \
                acc[mt][nt] = __builtin_amdgcn_mfma_f32_16x16x32_bf16(    \
                    af[mt].v, bf[nt].v, acc[mt][nt], 0, 0, 0);            \
    }                                                                     \
} while (0)

// 2-phase pipelined K-loop: stage tile t+1 BEFORE computing tile t; counted
// vmcnt(8) lets the 8 just-issued loads stay in flight across the barrier.
// (per-wave vmcnt correctness: each wave's OWN older 8 loads retired before
// its barrier arrival, so every staged chunk is visible after the barrier)
#define KLOOP(NK) do {                                                    \
    STAGE(As0, Bs0, 0);                                                   \
    for (int kt = 0; kt < (NK); kt += 2) {                                \
        STAGE(As1, Bs1, (kt + 1) * BK);                                   \
        asm volatile("s_waitcnt vmcnt(8)" ::: "memory");                  \
        __builtin_amdgcn_s_barrier();                                     \
        COMPUTE(As0, Bs0);                                                \
        __builtin_amdgcn_s_barrier();                                     \
        if (kt + 2 < (NK)) {                                              \
            STAGE(As0, Bs0, (kt + 2) * BK);                               \
            asm volatile("s_waitcnt vmcnt(8)" ::: "memory");              \
        } else {                                                          \
            asm volatile("s_waitcnt vmcnt(0)" ::: "memory");              \
        }                                                                 \
        __builtin_amdgcn_s_barrier();                                     \
        COMPUTE(As1, Bs1);                                                \
        __builtin_amdgcn_s_barrier();                                     \
    }                                                                     \
} while (0)

// -------- persistent expert up: [tokens]x[w1|w3 interleaved], K = C --------
// Work list: tile = mi*32 + nb over compacted (e,m-block) list; grid = 512
// always-active blocks (2/CU). Same-B blocks are 32 apart -> same XCD L2.
__global__ __launch_bounds__(256) void expert_up_kernel(
        const unsigned short* __restrict__ xb, const unsigned short* __restrict__ wt13,
        const float* __restrict__ b1, const float* __restrict__ b3,
        const int* __restrict__ counts, const int* __restrict__ lists,
        const int* __restrict__ plan, unsigned short* __restrict__ hbuf) {
    const int t = threadIdx.x;
    const int lane = t & 63, w = t >> 6;
    const int ln15 = lane & 15, lg = lane >> 4;
    const int wr = w >> 1, wc = w & 1;
    const int swz = ln15 & 7;

    __shared__ __align__(16) unsigned short As0[BM * BK], Bs0[BN * BK];
    __shared__ __align__(16) unsigned short As1[BM * BK], Bs1[BN * BK];
    __shared__ int rowtok[BM];

    const int ntile = plan[0] << 5;   // nmb * 32 n-blocks
    for (int tile = blockIdx.x; tile < ntile; tile += PGRID) {
        const int mi = tile >> 5, nb = tile & 31;
        const int ent = plan[1 + mi];
        const int e = ent >> 8, m0 = (ent & 255) * BM;
        const int cnt = counts[e];
        const int n0 = nb * BN;

        if (t < BM) {
            int r = m0 + t;  // tail rows duplicate last valid token (benign)
            rowtok[t] = lists[e * N_TOK + (r < cnt ? r : cnt - 1)];
        }
        __syncthreads();

        const unsigned short* wtb = wt13 + (size_t)e * (2 * H_DIM) * C_DIM;
        const unsigned short* asrc[4];
        const unsigned short* bsrc[4];
#pragma unroll
        for (int i = 0; i < 4; i++) {
            int c = i * 256 + w * 64 + lane;         // LDS chunk index (16B units)
            int row = c >> 3, slot = c & 7, kc = slot ^ (row & 7);
            asrc[i] = xb + (size_t)(rowtok[row] >> 2) * C_DIM + kc * 8;
            bsrc[i] = wtb + (size_t)(n0 + row) * C_DIM + kc * 8;
        }

        f32x4 acc[4][4];
#pragma unroll
        for (int a = 0; a < 4; a++)
#pragma unroll
            for (int b = 0; b < 4; b++) acc[a][b] = (f32x4){0.f, 0.f, 0.f, 0.f};

        KLOOP(C_DIM / BK);

        // epilogue: nt pairs (0,1),(2,3) are (a,g) for the same h column
#pragma unroll
        for (int p = 0; p < 2; p++) {
            int h = ((n0 + wc * 64 + p * 32) >> 5) * 16 + ln15;
            float bb1 = b1[e * H_DIM + h], bb3 = b3[e * H_DIM + h];
#pragma unroll
            for (int mt = 0; mt < 4; mt++) {
#pragma unroll
                for (int jj = 0; jj < 4; jj++) {
                    int mrow = wr * 64 + mt * 16 + lg * 4 + jj;  // C/D row=(lane>>4)*4+reg
                    float av = acc[mt][2 * p][jj] + bb1;
                    float gv = acc[mt][2 * p + 1][jj] + bb3;
                    float hv = av * gv / (1.f + __expf(-gv));    // silu(g)*a
                    int ent2 = rowtok[mrow];
                    hbuf[(size_t)((ent2 >> 2) * NSLOT + (ent2 & 3)) * H_DIM + h] = f2b(hv);
                }
            }
        }
        __syncthreads();   // protect rowtok/LDS before next tile
    }
}

// -------- persistent expert down: [h rows] x [w2^T], K = H --------
__global__ __launch_bounds__(256) void expert_down_kernel(
        const unsigned short* __restrict__ hbuf, const unsigned short* __restrict__ wt2t,
        const float* __restrict__ b2, const float* __restrict__ cw,
        const int* __restrict__ counts, const int* __restrict__ lists,
        const int* __restrict__ plan, float* __restrict__ outslot) {
    const int t = threadIdx.x;
    const int lane = t & 63, w = t >> 6;
    const int ln15 = lane & 15, lg = lane >> 4;
    const int wr = w >> 1, wc = w & 1;
    const int swz = ln15 & 7;

    __shared__ __align__(16) unsigned short As0[BM * BK], Bs0[BN * BK];
    __shared__ __align__(16) unsigned short As1[BM * BK], Bs1[BN * BK];
    __shared__ int rowtok[BM];

    const int ntile = plan[0] << 3;   // nmb * 8 c-blocks
    for (int tile = blockIdx.x; tile < ntile; tile += PGRID) {
        const int mi = tile >> 3, nb = tile & 7;
        const int ent = plan[1 + mi];
        const int e = ent >> 8, m0 = (ent & 255) * BM;
        const int cnt = counts[e];
        const int c0 = nb * BN;

        if (t < BM) {
            int r = m0 + t;
            rowtok[t] = lists[e * N_TOK + (r < cnt ? r : cnt - 1)];
        }
        __syncthreads();

        const unsigned short* wtb = wt2t + (size_t)e * C_DIM * H_DIM;
        const unsigned short* asrc[4];
        const unsigned short* bsrc[4];
#pragma unroll
        for (int i = 0; i < 4; i++) {
            int c = i * 256 + w * 64 + lane;
            int row = c >> 3, slot = c & 7, kc = slot ^ (row & 7);
            int ent2 = rowtok[row];
            asrc[i] = hbuf + (size_t)((ent2 >> 2) * NSLOT + (ent2 & 3)) * H_DIM + kc * 8;
            bsrc[i] = wtb + (size_t)(c0 + row) * H_DIM + kc * 8;
        }

        f32x4 acc[4][4];
#pragma unroll
        for (int a = 0; a < 4; a++)
#pragma unroll
            for (int b = 0; b < 4; b++) acc[a][b] = (f32x4){0.f, 0.f, 0.f, 0.f};

        KLOOP(H_DIM / BK);

#pragma unroll
        for (int nt = 0; nt < 4; nt++) {
            int col = c0 + wc * 64 + nt * 16 + ln15;
            float bb = b2[e * C_DIM + col];
#pragma unroll
            for (int mt = 0; mt < 4; mt++) {
#pragma unroll
                for (int jj = 0; jj < 4; jj++) {
                    int mrow = wr * 64 + mt * 16 + lg * 4 + jj;
                    int ent2 = rowtok[mrow];
                    int tok = ent2 >> 2, slot = ent2 & 3;
                    float cwv = cw[tok * NE + e];
                    outslot[(size_t)(tok * NSLOT + slot) * C_DIM + col] =
                        cwv * (acc[mt][nt][jj] + bb);
                }
            }
        }
        __syncthreads();
    }
}

__global__ __launch_bounds__(256) void reduce_kernel(
        const float* __restrict__ os, float* __restrict__ out) {
    int i = blockIdx.x * 256 + threadIdx.x;   // over N*C/4
    int n = i >> 8;
    int c = (i & 255) * 4;
    const float4 s0 = *(const float4*)(os + ((size_t)n * NSLOT + 0) * C_DIM + c);
    const float4 s1 = *(const float4*)(os + ((size_t)n * NSLOT + 1) * C_DIM + c);
    const float4 s2 = *(const float4*)(os + ((size_t)n * NSLOT + 2) * C_DIM + c);
    float4 r;
    r.x = s0.x + s1.x + s2.x; r.y = s0.y + s1.y + s2.y;
    r.z = s0.z + s1.z + s2.z; r.w = s0.w + s1.w + s2.w;
    *(float4*)(out + (size_t)n * C_DIM + c) = r;
}

__global__ void loss_kernel(const float* __restrict__ cw, const int* __restrict__ counts,
                            float* __restrict__ out) {
    int lane = threadIdx.x;
    float ss[NE];
#pragma unroll
    for (int e = 0; e < NE; e++) ss[e] = 0.f;
    for (int n = lane; n < N_TOK; n += 64) {
#pragma unroll
        for (int e = 0; e < NE; e++) ss[e] += cw[n * NE + e];
    }
#pragma unroll
    for (int e = 0; e < NE; e++) {
#pragma unroll
        for (int off = 32; off >= 1; off >>= 1) ss[e] += __shfl_xor(ss[e], off, 64);
    }
    if (lane == 0) {
        float bal = 0.f;
        const float fac = (float)NE / (3.f * (float)N_TOK * (float)N_TOK);
#pragma unroll
        for (int e = 0; e < NE; e++) bal += fac * (float)counts[e] * ss[e];
        out[(size_t)N_TOK * C_DIM] = bal;
    }
}

extern "C" void kernel_launch(void* const* d_in, const int* in_sizes, int n_in,
                              void* d_out, int out_size, void* d_ws, size_t ws_size,
                              hipStream_t stream) {
    const float* x  = (const float*)d_in[0];
    const float* gw = (const float*)d_in[1];
    const float* gb = (const float*)d_in[2];
    const float* w1 = (const float*)d_in[3];
    const float* b1 = (const float*)d_in[4];
    const float* w2 = (const float*)d_in[5];
    const float* b2 = (const float*)d_in[6];
    const float* w3 = (const float*)d_in[7];
    const float* b3 = (const float*)d_in[8];
    float* out = (float*)d_out;
    char* ws = (char*)d_ws;
    int*            counts = (int*)(ws + WS_COUNTS);
    int*            plan   = (int*)(ws + WS_PLAN);
    float*          cw     = (float*)(ws + WS_CW);
    int*            lists  = (int*)(ws + WS_LISTS);
    unsigned short* xb     = (unsigned short*)(ws + WS_XB);
    unsigned short* hbuf   = (unsigned short*)(ws + WS_HBUF);
    float*          oslot  = (float*)(ws + WS_OUTSLOT);
    unsigned short* wt13   = (unsigned short*)(ws + WS_WT13);
    unsigned short* wt2t   = (unsigned short*)(ws + WS_WT2T);

    hipLaunchKernelGGL(zero_kernel, dim3(1), dim3(64), 0, stream, counts);
    hipLaunchKernelGGL(gate_kernel, dim3(N_TOK / 4), dim3(256), 0, stream,
                       x, gw, gb, cw, xb, counts, lists);
    hipLaunchKernelGGL(plan_kernel, dim3(1), dim3(64), 0, stream, counts, plan);
    hipLaunchKernelGGL(tcast_all_kernel, dim3(C_DIM / 64, H_DIM / 64, NE * 3), dim3(256), 0, stream,
                       w1, w3, w2, wt13, wt2t);
    hipLaunchKernelGGL(expert_up_kernel, dim3(PGRID), dim3(256), 0, stream,
                       xb, wt13, b1, b3, counts, lists, plan, hbuf);
    hipLaunchKernelGGL(expert_down_kernel, dim3(PGRID), dim3(256), 0, stream,
                       hbuf, wt2t, b2, cw, counts, lists, plan, oslot);
    hipLaunchKernelGGL(reduce_kernel, dim3((N_TOK * C_DIM / 4) / 256), dim3(256), 0, stream,
                       oslot, out);
    hipLaunchKernelGGL(loss_kernel, dim3(1), dim3(64), 0, stream, cw, counts, out);
}

// Round 5
// 256.912 us; speedup vs baseline: 3.0078x; 1.3055x over previous
//
#include <hip/hip_runtime.h>
#include <stdint.h>

#define N_TOK 2048
#define C_DIM 1024
#define H_DIM 2048
#define NE 8
#define NSLOT 3

#define BM 128
#define BN 64
#define BK 64
#define PGRID 1024   // persistent: 256 CU x 4 resident (25KB LDS, <=128 VGPR)

// ws layout (bytes); every section multiple of 256
#define WS_COUNTS   0
#define WS_PLAN     256
#define WS_CW       (WS_PLAN + 1024)
#define WS_LISTS    (WS_CW + N_TOK*NE*4)
#define WS_XB       (WS_LISTS + NE*N_TOK*4)
#define WS_HBUF     (WS_XB + (size_t)N_TOK*C_DIM*2)
#define WS_OUTSLOT  (WS_HBUF + (size_t)N_TOK*NSLOT*H_DIM*2)
#define WS_WT13     (WS_OUTSLOT + (size_t)N_TOK*NSLOT*C_DIM*4)
#define WS_WT2T     (WS_WT13 + (size_t)NE*2*H_DIM*C_DIM*2)

typedef short bf16x8 __attribute__((ext_vector_type(8)));
typedef float f32x4 __attribute__((ext_vector_type(4)));

union FragU { bf16x8 v; uint2 u2[2]; };

__device__ __forceinline__ unsigned short f2b(float f) {
    union { float f; uint32_t u; } v; v.f = f;
    return (unsigned short)((v.u + 0x7fffu + ((v.u >> 16) & 1u)) >> 16); // RNE
}

// async global->LDS, 16B per lane; lds dest is wave-uniform base + lane*16
__device__ __forceinline__ void gload16(const unsigned short* g, unsigned short* l) {
    __builtin_amdgcn_global_load_lds(
        (const __attribute__((address_space(1))) unsigned int*)g,
        (__attribute__((address_space(3))) unsigned int*)l, 16, 0, 0);
}

__global__ void zero_kernel(int* counts) {
    if (threadIdx.x < NE) counts[threadIdx.x] = 0;
}

// ---------------- fused gate + weight tcast (independent work) ----------------
// blocks 0..511: gating (4 tokens/block, 1 wave/token)
// blocks 512..12799: transpose+cast weights to bf16 B^T layout
//   dst row r = ((n>>4)<<shift)+(n&15)+off; op0 w1->wt13, op1 w3->wt13(+16), op2 w2->wt2t
__global__ __launch_bounds__(256) void gate_tcast_kernel(
        const float* __restrict__ x, const float* __restrict__ gw,
        const float* __restrict__ gb, const float* __restrict__ w1,
        const float* __restrict__ w3, const float* __restrict__ w2,
        float* __restrict__ cw, unsigned short* __restrict__ xb,
        int* __restrict__ counts, int* __restrict__ lists,
        unsigned short* __restrict__ wt13, unsigned short* __restrict__ wt2t) {
    if (blockIdx.x < 512) {
        int n = (blockIdx.x * 256 + threadIdx.x) >> 6;
        int lane = threadIdx.x & 63;
        float acc[NE];
#pragma unroll
        for (int e = 0; e < NE; e++) acc[e] = 0.f;
        for (int c = lane; c < C_DIM; c += 64) {
            float xv = x[n * C_DIM + c];
            xb[n * C_DIM + c] = f2b(xv);
            const float* g = gw + c * NE;
#pragma unroll
            for (int e = 0; e < NE; e++) acc[e] += xv * g[e];
        }
#pragma unroll
        for (int e = 0; e < NE; e++) {
#pragma unroll
            for (int off = 32; off >= 1; off >>= 1) acc[e] += __shfl_xor(acc[e], off, 64);
            acc[e] += gb[e];
        }
        float m = acc[0];
#pragma unroll
        for (int e = 1; e < NE; e++) m = fmaxf(m, acc[e]);
        float s = 0.f, sc[NE];
#pragma unroll
        for (int e = 0; e < NE; e++) { sc[e] = __expf(acc[e] - m); s += sc[e]; }
        float inv = 1.f / s;
#pragma unroll
        for (int e = 0; e < NE; e++) sc[e] *= inv;
        // top-2 of routed experts 1..7; ties -> lower index (matches lax.top_k)
        int i1 = 1; float v1 = sc[1];
#pragma unroll
        for (int e = 2; e < NE; e++) if (sc[e] > v1) { v1 = sc[e]; i1 = e; }
        int i2 = 0; float v2 = -1.f;
#pragma unroll
        for (int e = 1; e < NE; e++) if (e != i1 && sc[e] > v2) { v2 = sc[e]; i2 = e; }
        if (lane < NE) {
            float v = 0.f;
            if (lane == 0) v = sc[0];
            else if (lane == i1) v = v1;
            else if (lane == i2) v = v2;
            cw[n * NE + lane] = v;
        }
        if (lane == 0) {  // entry = token*4 + slot
            int p0 = atomicAdd(&counts[0], 1);  lists[p0] = n * 4 + 0;
            int p1 = atomicAdd(&counts[i1], 1); lists[i1 * N_TOK + p1] = n * 4 + 1;
            int p2 = atomicAdd(&counts[i2], 1); lists[i2 * N_TOK + p2] = n * 4 + 2;
        }
    } else {
        int bb = blockIdx.x - 512;
        int z = bb >> 9, tb = bb & 511;          // z in [0,24): op = z%3, e = z/3
        int op = z % 3, e = z / 3;
        const float* src; unsigned short* dst;
        int K, N, Nr, shift, off, k0, n0;
        if (op < 2) {
            src = op ? w3 : w1; dst = wt13;
            K = C_DIM; N = H_DIM; Nr = 2 * H_DIM; shift = 5; off = op ? 16 : 0;
            k0 = (tb & 15) * 64; n0 = (tb >> 4) * 64;
        } else {
            src = w2; dst = wt2t;
            K = H_DIM; N = C_DIM; Nr = C_DIM; shift = 4; off = 0;
            k0 = (tb >> 4) * 64; n0 = (tb & 15) * 64;
        }
        __shared__ unsigned short tile[64][72];
        const float* s = src + ((size_t)e * K + k0) * N + n0;
        int tr = threadIdx.x >> 4, tc = (threadIdx.x & 15) * 4;
#pragma unroll
        for (int i = 0; i < 4; i++) {
            float4 v = *(const float4*)(s + (size_t)(tr + i * 16) * N + tc);
            tile[tr + i * 16][tc + 0] = f2b(v.x);
            tile[tr + i * 16][tc + 1] = f2b(v.y);
            tile[tr + i * 16][tc + 2] = f2b(v.z);
            tile[tr + i * 16][tc + 3] = f2b(v.w);
        }
        __syncthreads();
        int hl = threadIdx.x >> 3, kl = (threadIdx.x & 7) * 8;
#pragma unroll
        for (int i = 0; i < 2; i++) {
            int hloc = hl + i * 32;
            int n = n0 + hloc;
            int r = ((n >> 4) << shift) + (n & 15) + off;
            unsigned short tmp[8];
#pragma unroll
            for (int q = 0; q < 8; q++) tmp[q] = tile[kl + q][hloc];
            *(uint4*)(dst + ((size_t)e * Nr + r) * K + k0 + kl) = *(uint4*)tmp;
        }
    }
}

// ---------------- plan: compacted (expert, m-block) work list ----------------
__global__ void plan_kernel(const int* __restrict__ counts, int* __restrict__ plan) {
    if (threadIdx.x == 0) {
        int p = 0;
        for (int e = 0; e < NE; e++) {
            int nb = (counts[e] + BM - 1) / BM;
            for (int m = 0; m < nb; m++) plan[1 + p++] = (e << 8) | m;
        }
        plan[0] = p;
    }
}

// STAGE: 4 A-chunks + 2 B-chunks per lane (async 16B global->LDS)
#define STAGE(koff) do {                                                  \
    _Pragma("unroll")                                                     \
    for (int i_ = 0; i_ < 4; i_++)                                        \
        gload16(asrc[i_] + (koff), As + (i_ * 256 + t) * 8);              \
    _Pragma("unroll")                                                     \
    for (int i_ = 0; i_ < 2; i_++)                                        \
        gload16(bsrc[i_] + (koff), Bs + (i_ * 256 + t) * 8);              \
} while (0)

// COMPUTE: 12 ds_read_b128 + 16 MFMA on one 128x64x64 tile (wave tile 64x32)
#define COMPUTE() do {                                                    \
    __builtin_amdgcn_s_setprio(1);                                        \
    _Pragma("unroll")                                                     \
    for (int j_ = 0; j_ < 2; j_++) {                                      \
        FragU af[4], bf[2];                                               \
        _Pragma("unroll")                                                 \
        for (int mt = 0; mt < 4; mt++) {                                  \
            int row = wr * 64 + mt * 16 + ln15;                           \
            int slot = (j_ * 4 + lg) ^ swz;                               \
            af[mt].v = *(const bf16x8*)(As + row * BK + slot * 8);        \
        }                                                                 \
        _Pragma("unroll")                                                 \
        for (int nt = 0; nt < 2; nt++) {                                  \
            int row = wc * 32 + nt * 16 + ln15;                           \
            int slot = (j_ * 4 + lg) ^ swz;                               \
            bf[nt].v = *(const bf16x8*)(Bs + row * BK + slot * 8);        \
        }                                                                 \
        _Pragma("unroll")                                                 \
        for (int mt = 0; mt < 4; mt++)                                    \
            _Pragma("unroll")                                             \
            for (int nt = 0; nt < 2; nt++)                                \
                acc[mt][nt] = __builtin_amdgcn_mfma_f32_16x16x32_bf16(    \
                    af[mt].v, bf[nt].v, acc[mt][nt], 0, 0, 0);            \
    }                                                                     \
    __builtin_amdgcn_s_setprio(0);                                        \
} while (0)

// single-buffer K-loop: drain own loads, barrier, compute, barrier.
// Latency hiding comes from 4 blocks/CU TLP (m114 mechanism), not ILP.
#define KLOOP(NK) do {                                                    \
    for (int kt = 0; kt < (NK); kt++) {                                   \
        STAGE(kt * BK);                                                   \
        asm volatile("s_waitcnt vmcnt(0)" ::: "memory");                  \
        __builtin_amdgcn_s_barrier();                                     \
        COMPUTE();                                                        \
        __builtin_amdgcn_s_barrier();                                     \
    }                                                                     \
} while (0)

// -------- persistent expert up: [tokens]x[w1|w3 interleaved], K = C --------
// tile = mi*64 + nb; same-B blocks 64 apart -> same XCD L2.
__global__ __launch_bounds__(256, 4) void expert_up_kernel(
        const unsigned short* __restrict__ xb, const unsigned short* __restrict__ wt13,
        const float* __restrict__ b1, const float* __restrict__ b3,
        const int* __restrict__ counts, const int* __restrict__ lists,
        const int* __restrict__ plan, unsigned short* __restrict__ hbuf) {
    const int t = threadIdx.x;
    const int lane = t & 63, w = t >> 6;
    const int ln15 = lane & 15, lg = lane >> 4;
    const int wr = w >> 1, wc = w & 1;
    const int swz = ln15 & 7;

    __shared__ __align__(16) unsigned short As[BM * BK];  // 16 KB
    __shared__ __align__(16) unsigned short Bs[BN * BK];  // 8 KB
    __shared__ int rowtok[BM];

    const int ntile = plan[0] << 6;   // nmb * 64 n-blocks (N = 2H = 4096)
    for (int tile = blockIdx.x; tile < ntile; tile += PGRID) {
        const int mi = tile >> 6, nb = tile & 63;
        const int ent = plan[1 + mi];
        const int e = ent >> 8, m0 = (ent & 255) * BM;
        const int cnt = counts[e];
        const int n0 = nb * BN;

        if (t < BM) {
            int r = m0 + t;  // tail rows duplicate last valid token (benign)
            rowtok[t] = lists[e * N_TOK + (r < cnt ? r : cnt - 1)];
        }
        __syncthreads();

        const unsigned short* wtb = wt13 + (size_t)e * (2 * H_DIM) * C_DIM;
        const unsigned short* asrc[4];
        const unsigned short* bsrc[2];
#pragma unroll
        for (int i = 0; i < 4; i++) {   // A chunk c: row=c>>3, holds kc=(c&7)^(row&7)
            int c = i * 256 + t;
            int row = c >> 3, kc = (c & 7) ^ (row & 7);
            asrc[i] = xb + (size_t)(rowtok[row] >> 2) * C_DIM + kc * 8;
        }
#pragma unroll
        for (int i = 0; i < 2; i++) {
            int c = i * 256 + t;
            int row = c >> 3, kc = (c & 7) ^ (row & 7);
            bsrc[i] = wtb + (size_t)(n0 + row) * C_DIM + kc * 8;
        }

        f32x4 acc[4][2];
#pragma unroll
        for (int a = 0; a < 4; a++)
#pragma unroll
            for (int b = 0; b < 2; b++) acc[a][b] = (f32x4){0.f, 0.f, 0.f, 0.f};

        KLOOP(C_DIM / BK);

        // epilogue: wave's 32 B-rows = one 32-group: nt=0 -> w1 (a), nt=1 -> w3 (g)
        {
            int h = ((n0 + wc * 32) >> 5) * 16 + ln15;
            float bb1 = b1[e * H_DIM + h], bb3 = b3[e * H_DIM + h];
#pragma unroll
            for (int mt = 0; mt < 4; mt++) {
#pragma unroll
                for (int jj = 0; jj < 4; jj++) {
                    int mrow = wr * 64 + mt * 16 + lg * 4 + jj;  // C/D row=(lane>>4)*4+reg
                    float av = acc[mt][0][jj] + bb1;
                    float gv = acc[mt][1][jj] + bb3;
                    float hv = av * gv / (1.f + __expf(-gv));    // silu(g)*a
                    int ent2 = rowtok[mrow];
                    hbuf[(size_t)((ent2 >> 2) * NSLOT + (ent2 & 3)) * H_DIM + h] = f2b(hv);
                }
            }
        }
        __syncthreads();   // protect rowtok/LDS before next tile
    }
}

// -------- persistent expert down: [h rows] x [w2^T], K = H --------
__global__ __launch_bounds__(256, 4) void expert_down_kernel(
        const unsigned short* __restrict__ hbuf, const unsigned short* __restrict__ wt2t,
        const float* __restrict__ b2, const float* __restrict__ cw,
        const int* __restrict__ counts, const int* __restrict__ lists,
        const int* __restrict__ plan, float* __restrict__ outslot) {
    const int t = threadIdx.x;
    const int lane = t & 63, w = t >> 6;
    const int ln15 = lane & 15, lg = lane >> 4;
    const int wr = w >> 1, wc = w & 1;
    const int swz = ln15 & 7;

    __shared__ __align__(16) unsigned short As[BM * BK];
    __shared__ __align__(16) unsigned short Bs[BN * BK];
    __shared__ int rowtok[BM];

    const int ntile = plan[0] << 4;   // nmb * 16 c-blocks (N = C = 1024)
    for (int tile = blockIdx.x; tile < ntile; tile += PGRID) {
        const int mi = tile >> 4, nb = tile & 15;
        const int ent = plan[1 + mi];
        const int e = ent >> 8, m0 = (ent & 255) * BM;
        const int cnt = counts[e];
        const int c0 = nb * BN;

        if (t < BM) {
            int r = m0 + t;
            rowtok[t] = lists[e * N_TOK + (r < cnt ? r : cnt - 1)];
        }
        __syncthreads();

        const unsigned short* wtb = wt2t + (size_t)e * C_DIM * H_DIM;
        const unsigned short* asrc[4];
        const unsigned short* bsrc[2];
#pragma unroll
        for (int i = 0; i < 4; i++) {
            int c = i * 256 + t;
            int row = c >> 3, kc = (c & 7) ^ (row & 7);
            int ent2 = rowtok[row];
            asrc[i] = hbuf + (size_t)((ent2 >> 2) * NSLOT + (ent2 & 3)) * H_DIM + kc * 8;
        }
#pragma unroll
        for (int i = 0; i < 2; i++) {
            int c = i * 256 + t;
            int row = c >> 3, kc = (c & 7) ^ (row & 7);
            bsrc[i] = wtb + (size_t)(c0 + row) * H_DIM + kc * 8;
        }

        f32x4 acc[4][2];
#pragma unroll
        for (int a = 0; a < 4; a++)
#pragma unroll
            for (int b = 0; b < 2; b++) acc[a][b] = (f32x4){0.f, 0.f, 0.f, 0.f};

        KLOOP(H_DIM / BK);

#pragma unroll
        for (int nt = 0; nt < 2; nt++) {
            int col = c0 + wc * 32 + nt * 16 + ln15;
            float bb = b2[e * C_DIM + col];
#pragma unroll
            for (int mt = 0; mt < 4; mt++) {
#pragma unroll
                for (int jj = 0; jj < 4; jj++) {
                    int mrow = wr * 64 + mt * 16 + lg * 4 + jj;
                    int ent2 = rowtok[mrow];
                    int tok = ent2 >> 2, slot = ent2 & 3;
                    float cwv = cw[tok * NE + e];
                    outslot[(size_t)(tok * NSLOT + slot) * C_DIM + col] =
                        cwv * (acc[mt][nt][jj] + bb);
                }
            }
        }
        __syncthreads();
    }
}

// -------- fused reduce (blocks 0..2047) + balance loss (block 2048) --------
__global__ __launch_bounds__(256) void reduce_loss_kernel(
        const float* __restrict__ os, const float* __restrict__ cw,
        const int* __restrict__ counts, float* __restrict__ out) {
    if (blockIdx.x < 2048) {
        int i = blockIdx.x * 256 + threadIdx.x;   // over N*C/4
        int n = i >> 8;
        int c = (i & 255) * 4;
        const float4 s0 = *(const float4*)(os + ((size_t)n * NSLOT + 0) * C_DIM + c);
        const float4 s1 = *(const float4*)(os + ((size_t)n * NSLOT + 1) * C_DIM + c);
        const float4 s2 = *(const float4*)(os + ((size_t)n * NSLOT + 2) * C_DIM + c);
        float4 r;
        r.x = s0.x + s1.x + s2.x; r.y = s0.y + s1.y + s2.y;
        r.z = s0.z + s1.z + s2.z; r.w = s0.w + s1.w + s2.w;
        *(float4*)(out + (size_t)n * C_DIM + c) = r;
    } else if (threadIdx.x < 64) {
        int lane = threadIdx.x;
        float ss[NE];
#pragma unroll
        for (int e = 0; e < NE; e++) ss[e] = 0.f;
        for (int n = lane; n < N_TOK; n += 64) {
#pragma unroll
            for (int e = 0; e < NE; e++) ss[e] += cw[n * NE + e];
        }
#pragma unroll
        for (int e = 0; e < NE; e++) {
#pragma unroll
            for (int off = 32; off >= 1; off >>= 1) ss[e] += __shfl_xor(ss[e], off, 64);
        }
        if (lane == 0) {
            float bal = 0.f;
            const float fac = (float)NE / (3.f * (float)N_TOK * (float)N_TOK);
#pragma unroll
            for (int e = 0; e < NE; e++) bal += fac * (float)counts[e] * ss[e];
            out[(size_t)N_TOK * C_DIM] = bal;
        }
    }
}

extern "C" void kernel_launch(void* const* d_in, const int* in_sizes, int n_in,
                              void* d_out, int out_size, void* d_ws, size_t ws_size,
                              hipStream_t stream) {
    const float* x  = (const float*)d_in[0];
    const float* gw = (const float*)d_in[1];
    const float* gb = (const float*)d_in[2];
    const float* w1 = (const float*)d_in[3];
    const float* b1 = (const float*)d_in[4];
    const float* w2 = (const float*)d_in[5];
    const float* b2 = (const float*)d_in[6];
    const float* w3 = (const float*)d_in[7];
    const float* b3 = (const float*)d_in[8];
    float* out = (float*)d_out;
    char* ws = (char*)d_ws;
    int*            counts = (int*)(ws + WS_COUNTS);
    int*            plan   = (int*)(ws + WS_PLAN);
    float*          cw     = (float*)(ws + WS_CW);
    int*            lists  = (int*)(ws + WS_LISTS);
    unsigned short* xb     = (unsigned short*)(ws + WS_XB);
    unsigned short* hbuf   = (unsigned short*)(ws + WS_HBUF);
    float*          oslot  = (float*)(ws + WS_OUTSLOT);
    unsigned short* wt13   = (unsigned short*)(ws + WS_WT13);
    unsigned short* wt2t   = (unsigned short*)(ws + WS_WT2T);

    hipLaunchKernelGGL(zero_kernel, dim3(1), dim3(64), 0, stream, counts);
    hipLaunchKernelGGL(gate_tcast_kernel, dim3(512 + 24 * 512), dim3(256), 0, stream,
                       x, gw, gb, w1, w3, w2, cw, xb, counts, lists, wt13, wt2t);
    hipLaunchKernelGGL(plan_kernel, dim3(1), dim3(64), 0, stream, counts, plan);
    hipLaunchKernelGGL(expert_up_kernel, dim3(PGRID), dim3(256), 0, stream,
                       xb, wt13, b1, b3, counts, lists, plan, hbuf);
    hipLaunchKernelGGL(expert_down_kernel, dim3(PGRID), dim3(256), 0, stream,
                       hbuf, wt2t, b2, cw, counts, lists, plan, oslot);
    hipLaunchKernelGGL(reduce_loss_kernel, dim3(2049), dim3(256), 0, stream,
                       oslot, cw, counts, out);
}